// Round 2
// baseline (691.620 us; speedup 1.0000x reference)
//
#include <hip/hip_runtime.h>

#define V 86
#define VP 96              // padded vertex count
#define CIN 64
#define COUT 128
#define NSTAT (32*256*86)  // 704512

// workspace offsets (bytes)
#define OFF_FLAG  0        // int: 1 = bf16 tensors, 0 = float32 tensors
#define OFF_NADJ  512      // bf16 [96][96] zero-padded norm_adj (18432 B)
#define OFF_WT    19456    // bf16 [128][64] w transposed [d][c] (16384 B)
#define OFF_GSUM  35840    // float[128]
#define OFF_GSQ   36352    // float[128]
#define OFF_SCALE 36864    // float[128]
#define OFF_SHIFT 37376    // float[128]

typedef short short8 __attribute__((ext_vector_type(8)));
typedef float float4v __attribute__((ext_vector_type(4)));

static __device__ __forceinline__ float bf2f(ushort u) {
    union { uint i; float f; } c; c.i = ((uint)u) << 16; return c.f;
}
static __device__ __forceinline__ ushort f2bf(float f) {
    union { float f; uint i; } c; c.f = f;
    uint u = c.i;
    uint r = u + 0x7FFFu + ((u >> 16) & 1u);   // RNE
    return (ushort)(r >> 16);
}
static __device__ __forceinline__ uint packbf(float a, float b) {
    return (uint)f2bf(a) | ((uint)f2bf(b) << 16);
}
template<bool BF>
static __device__ __forceinline__ float ldg(const void* p, int i) {
    if (BF) return bf2f(((const ushort*)p)[i]);
    else    return ((const float*)p)[i];
}

// ---------------- K0: detect tensor dtype from adj bit patterns ----------------
__global__ void k0_detect(const uint* __restrict__ adj_raw, char* __restrict__ ws) {
    __shared__ int s_found;
    if (threadIdx.x == 0) s_found = 0;
    __syncthreads();
    int found = 0;
    for (int i = threadIdx.x; i < 3698; i += blockDim.x) {
        uint wd = adj_raw[i];
        if (wd == 0x00003F80u || wd == 0x3F803F80u) found = 1;
    }
    if (found) atomicOr(&s_found, 1);
    __syncthreads();
    if (threadIdx.x == 0) *(int*)(ws + OFF_FLAG) = s_found;
}

// ---------------- K1: dense padded norm_adj (bf16) + wT + zero stats ----------------
template<bool BF>
__global__ void k1_prep(const void* __restrict__ adj, const void* __restrict__ w,
                        char* __restrict__ ws) {
    const int flag = *(const volatile int*)(ws + OFF_FLAG);
    if ((flag != 0) != BF) return;
    __shared__ float dinv[V];
    const int t = threadIdx.x;
    ushort* nadj = (ushort*)(ws + OFF_NADJ);
    ushort* wT   = (ushort*)(ws + OFF_WT);
    float*  gsum = (float*)(ws + OFF_GSUM);
    float*  gsq  = (float*)(ws + OFF_GSQ);

    if (t < V) {
        float s = 0.f;
        for (int v2 = 0; v2 < V; ++v2)
            s += ldg<BF>(adj, t * V + v2) + (v2 == t ? 1.f : 0.f);
        dinv[t] = rsqrtf(s);
    }
    __syncthreads();
    // dense padded nadj[u][v] = dinv[u]*(a+I)*dinv[v], zero for u,v >= 86
    for (int i = t; i < VP * VP; i += blockDim.x) {
        int u = i / VP, v2 = i % VP;
        float val = 0.f;
        if (u < V && v2 < V) {
            float a = ldg<BF>(adj, u * V + v2) + (v2 == u ? 1.f : 0.f);
            val = dinv[u] * a * dinv[v2];
        }
        nadj[i] = f2bf(val);
    }
    // w [c][d] -> wT [d][c] bf16
    for (int i = t; i < CIN * COUT; i += blockDim.x) {
        int cc = i >> 7, d = i & 127;
        wT[d * CIN + cc] = BF ? ((const ushort*)w)[i] : f2bf(((const float*)w)[i]);
    }
    if (t < COUT) { gsum[t] = 0.f; gsq[t] = 0.f; }
}

// ---------------- K2 pass: z = nadj @ (x @ w), all-MFMA, 8 bt per block ----------------
// STATS=true: accumulate sum/sumsq AND store raw z to out (BN applied later by k4).
// (STATS=false branch kept for reference; not launched.)
#define NJ_STR 104   // shorts; 208 B rows: 16B-aligned, 2-way bank alias only
#define XS_STR 72    // 144 B rows
#define YT_STR 104

template<bool BF, bool STATS>
__global__ __launch_bounds__(512, 4) void k2_pass(const void* __restrict__ x,
                                                  char* __restrict__ ws,
                                                  void* __restrict__ outv) {
    const int flag = *(const volatile int*)(ws + OFF_FLAG);
    if ((flag != 0) != BF) return;

    __shared__ __align__(16) short s_nadj[VP * NJ_STR];   // 19968 B
    __shared__ __align__(16) short s_x[VP * XS_STR];      // 13824 B
    __shared__ __align__(16) short s_yT[COUT * YT_STR];   // 26624 B

    const int tid  = threadIdx.x;
    const int lane = tid & 63, wv = tid >> 6;     // 8 waves
    const int col  = lane & 15, quad = lane >> 4;
    const int d_own = wv * 16 + col;              // this lane's output channel

    // nadj -> LDS once per block (global [96][96] -> [96][104])
    {
        const ushort* g = (const ushort*)(ws + OFF_NADJ);
        for (int i = tid; i < VP * 12; i += 512) {   // 12 x uint4 (8 shorts) per row
            int r = i / 12, j = i % 12;
            *(uint4*)&s_nadj[r * NJ_STR + j * 8] = *(const uint4*)&g[r * VP + j * 8];
        }
    }
    // w B-fragments live in registers for the whole kernel
    short8 bw[2];
    {
        const ushort* wt = (const ushort*)(ws + OFF_WT);
        bw[0] = *(const short8*)&wt[d_own * CIN + quad * 8];
        bw[1] = *(const short8*)&wt[d_own * CIN + 32 + quad * 8];
    }
    // zero-pad x rows 86..95 (written once; x loads only touch rows < 86)
    if (tid < 160) {
        int r = V + (tid >> 4), j = tid & 15;
        *(uint2*)&s_x[r * XS_STR + j * 4] = (uint2){0u, 0u};
    }
    float sc = 0.f, sh = 0.f;
    if (!STATS) {
        sc = ((const float*)(ws + OFF_SCALE))[d_own];
        sh = ((const float*)(ws + OFF_SHIFT))[d_own];
    }
    float s1 = 0.f, s2 = 0.f;

    for (int ib = 0; ib < 8; ++ib) {
        const int bt = blockIdx.x * 8 + ib;
        __syncthreads();   // guards s_x / s_yT reuse across iterations

        // ---- x slice -> LDS bf16 [86][64] ----
        if (BF) {
            const ushort* xg = (const ushort*)x + (size_t)bt * (V * CIN);
            for (int i = tid; i < V * 8; i += 512) {     // 688 x uint4
                int r = i >> 3, j = i & 7;
                *(uint4*)&s_x[r * XS_STR + j * 8] = *(const uint4*)&xg[r * CIN + j * 8];
            }
        } else {
            const float* xg = (const float*)x + (size_t)bt * (V * CIN);
            for (int i = tid; i < V * 16; i += 512) {    // 1376 x float4 -> uint2
                int r = i >> 4, j = i & 15;
                float4 f = *(const float4*)&xg[r * CIN + j * 4];
                uint2 o; o.x = packbf(f.x, f.y); o.y = packbf(f.z, f.w);
                *(uint2*)&s_x[r * XS_STR + j * 4] = o;
            }
        }
        __syncthreads();

        // ---- stage A: y = x @ w  (M=96 rows v, N=16 own d-tile, K=64) ----
        float4v accy[6];
        #pragma unroll
        for (int m = 0; m < 6; ++m) accy[m] = (float4v){0.f, 0.f, 0.f, 0.f};
        #pragma unroll
        for (int ks = 0; ks < 2; ++ks) {
            #pragma unroll
            for (int m = 0; m < 6; ++m) {
                short8 ax = *(const short8*)&s_x[(m * 16 + col) * XS_STR + ks * 32 + quad * 8];
                accy[m] = __builtin_amdgcn_mfma_f32_16x16x32_bf16(ax, bw[ks], accy[m], 0, 0, 0);
            }
        }
        // y D-frags -> yT[d][v] (transposed so stage-B B-frags are k-contiguous)
        #pragma unroll
        for (int m = 0; m < 6; ++m)
            #pragma unroll
            for (int r = 0; r < 4; ++r)
                s_yT[d_own * YT_STR + m * 16 + quad * 4 + r] = (short)f2bf(accy[m][r]);
        __syncthreads();

        // ---- stage B: z = nadj @ y  (M=96 rows u, N=16 own d-tile, K=96) ----
        float4v accz[6];
        #pragma unroll
        for (int m = 0; m < 6; ++m) accz[m] = (float4v){0.f, 0.f, 0.f, 0.f};
        #pragma unroll
        for (int ks = 0; ks < 3; ++ks) {
            short8 by = *(const short8*)&s_yT[d_own * YT_STR + ks * 32 + quad * 8];
            #pragma unroll
            for (int m = 0; m < 6; ++m) {
                short8 an = *(const short8*)&s_nadj[(m * 16 + col) * NJ_STR + ks * 32 + quad * 8];
                accz[m] = __builtin_amdgcn_mfma_f32_16x16x32_bf16(an, by, accz[m], 0, 0, 0);
            }
        }

        // ---- epilogue (D-frag: row u = m*16+quad*4+r, col d_own) ----
        if (STATS) {
            // stats + raw z store (BN+ReLU applied in-place later by k4_bn)
            const size_t base = (size_t)bt * (V * COUT) + d_own;
            #pragma unroll
            for (int m = 0; m < 6; ++m)
                #pragma unroll
                for (int r = 0; r < 4; ++r) {
                    int u = m * 16 + quad * 4 + r;
                    if (u < V) {
                        float v2 = accz[m][r];
                        s1 += v2; s2 += v2 * v2;
                        if (BF) ((ushort*)outv)[base + (size_t)u * COUT] = f2bf(v2);
                        else    ((float*)outv)[base + (size_t)u * COUT]  = v2;
                    }
                }
        } else {
            const size_t base = (size_t)bt * (V * COUT) + d_own;
            #pragma unroll
            for (int m = 0; m < 6; ++m)
                #pragma unroll
                for (int r = 0; r < 4; ++r) {
                    int u = m * 16 + quad * 4 + r;
                    if (u < V) {
                        float val = fmaxf(accz[m][r] * sc + sh, 0.f);
                        if (BF) ((ushort*)outv)[base + (size_t)u * COUT] = f2bf(val);
                        else    ((float*)outv)[base + (size_t)u * COUT]  = val;
                    }
                }
        }
    }

    if (STATS) {
        // reduce over the 4 quads sharing d_own, then one atomic per channel per block
        s1 += __shfl_xor(s1, 16); s1 += __shfl_xor(s1, 32);
        s2 += __shfl_xor(s2, 16); s2 += __shfl_xor(s2, 32);
        if (quad == 0) {
            atomicAdd((float*)(ws + OFF_GSUM) + d_own, s1);
            atomicAdd((float*)(ws + OFF_GSQ)  + d_own, s2);
        }
    }
}

// ---------------- K3: finalize BN scale/shift ----------------
template<bool BF>
__global__ void k3_finalize(const void* __restrict__ gamma, const void* __restrict__ beta,
                            char* __restrict__ ws) {
    const int flag = *(const volatile int*)(ws + OFF_FLAG);
    if ((flag != 0) != BF) return;
    int d = threadIdx.x;
    if (d < COUT) {
        const float* gsum = (const float*)(ws + OFF_GSUM);
        const float* gsq  = (const float*)(ws + OFF_GSQ);
        float* scale = (float*)(ws + OFF_SCALE);
        float* shift = (float*)(ws + OFF_SHIFT);
        const float inv_n = 1.f / (float)NSTAT;
        float mean = gsum[d] * inv_n;
        float var  = gsq[d] * inv_n - mean * mean;
        float s    = ldg<BF>(gamma, d) * rsqrtf(var + 1e-5f);
        scale[d] = s;
        shift[d] = ldg<BF>(beta, d) - mean * s;
    }
}

// ---------------- K4: in-place BN scale/shift + ReLU over d_out ----------------
// 16 threads per 128-channel row, 8 channels each (16 B bf16 / 32 B f32).
// Consecutive lanes cover contiguous memory -> fully coalesced RMW.
template<bool BF>
__global__ __launch_bounds__(256) void k4_bn(char* __restrict__ ws, void* __restrict__ outv) {
    const int flag = *(const volatile int*)(ws + OFF_FLAG);
    if ((flag != 0) != BF) return;
    const float* scale = (const float*)(ws + OFF_SCALE);
    const float* shift = (const float*)(ws + OFF_SHIFT);
    const int d8 = threadIdx.x & 15;
    float sc[8], sh[8];
    #pragma unroll
    for (int j = 0; j < 8; ++j) { sc[j] = scale[d8 * 8 + j]; sh[j] = shift[d8 * 8 + j]; }
    const int nrows = 8192 * V;                       // 704512
    const int rstride = (gridDim.x * blockDim.x) >> 4;
    int row = (blockIdx.x * blockDim.x + threadIdx.x) >> 4;
    for (; row < nrows; row += rstride) {
        if (BF) {
            uint4* p = (uint4*)((ushort*)outv + (size_t)row * COUT + d8 * 8);
            uint4 v = *p;
            float f0 = bf2f((ushort)v.x), f1 = bf2f((ushort)(v.x >> 16));
            float f2 = bf2f((ushort)v.y), f3 = bf2f((ushort)(v.y >> 16));
            float f4 = bf2f((ushort)v.z), f5 = bf2f((ushort)(v.z >> 16));
            float f6 = bf2f((ushort)v.w), f7 = bf2f((ushort)(v.w >> 16));
            f0 = fmaxf(fmaf(f0, sc[0], sh[0]), 0.f);
            f1 = fmaxf(fmaf(f1, sc[1], sh[1]), 0.f);
            f2 = fmaxf(fmaf(f2, sc[2], sh[2]), 0.f);
            f3 = fmaxf(fmaf(f3, sc[3], sh[3]), 0.f);
            f4 = fmaxf(fmaf(f4, sc[4], sh[4]), 0.f);
            f5 = fmaxf(fmaf(f5, sc[5], sh[5]), 0.f);
            f6 = fmaxf(fmaf(f6, sc[6], sh[6]), 0.f);
            f7 = fmaxf(fmaf(f7, sc[7], sh[7]), 0.f);
            uint4 o;
            o.x = packbf(f0, f1); o.y = packbf(f2, f3);
            o.z = packbf(f4, f5); o.w = packbf(f6, f7);
            *p = o;
        } else {
            float4* p = (float4*)((float*)outv + (size_t)row * COUT + d8 * 8);
            float4 a = p[0], b = p[1];
            a.x = fmaxf(fmaf(a.x, sc[0], sh[0]), 0.f);
            a.y = fmaxf(fmaf(a.y, sc[1], sh[1]), 0.f);
            a.z = fmaxf(fmaf(a.z, sc[2], sh[2]), 0.f);
            a.w = fmaxf(fmaf(a.w, sc[3], sh[3]), 0.f);
            b.x = fmaxf(fmaf(b.x, sc[4], sh[4]), 0.f);
            b.y = fmaxf(fmaf(b.y, sc[5], sh[5]), 0.f);
            b.z = fmaxf(fmaf(b.z, sc[6], sh[6]), 0.f);
            b.w = fmaxf(fmaf(b.w, sc[7], sh[7]), 0.f);
            p[0] = a; p[1] = b;
        }
    }
}

extern "C" void kernel_launch(void* const* d_in, const int* in_sizes, int n_in,
                              void* d_out, int out_size, void* d_ws, size_t ws_size,
                              hipStream_t stream) {
    const void* x     = d_in[0];
    const void* adj   = d_in[1];
    const void* w     = d_in[2];
    const void* gamma = d_in[3];
    const void* beta  = d_in[4];
    char* ws = (char*)d_ws;

    hipLaunchKernelGGL(k0_detect, dim3(1), dim3(256), 0, stream, (const uint*)adj, ws);
    hipLaunchKernelGGL((k1_prep<true>),  dim3(1), dim3(256), 0, stream, adj, w, ws);
    hipLaunchKernelGGL((k1_prep<false>), dim3(1), dim3(256), 0, stream, adj, w, ws);
    // single MFMA pass: stats -> ws, raw z -> d_out
    hipLaunchKernelGGL((k2_pass<true,  true>),  dim3(1024), dim3(512), 0, stream, x, ws, d_out);
    hipLaunchKernelGGL((k2_pass<false, true>),  dim3(1024), dim3(512), 0, stream, x, ws, d_out);
    hipLaunchKernelGGL((k3_finalize<true>),  dim3(1), dim3(128), 0, stream, gamma, beta, ws);
    hipLaunchKernelGGL((k3_finalize<false>), dim3(1), dim3(128), 0, stream, gamma, beta, ws);
    // elementwise in-place BN + ReLU
    hipLaunchKernelGGL((k4_bn<true>),  dim3(2048), dim3(256), 0, stream, ws, d_out);
    hipLaunchKernelGGL((k4_bn<false>), dim3(2048), dim3(256), 0, stream, ws, d_out);
}

// Round 4
// 617.125 us; speedup vs baseline: 1.1207x; 1.1207x over previous
//
#include <hip/hip_runtime.h>

#define V 86
#define VP 96              // padded vertex count
#define CIN 64
#define COUT 128
#define BT 8192            // 32*256
#define NSTAT (32*256*86)  // 704512

// workspace offsets (bytes)
#define OFF_FLAG  0        // int: 1 = bf16 tensors, 0 = float32 tensors
#define OFF_NADJ  512      // bf16 [96][96] zero-padded norm_adj (18432 B)
#define OFF_WT    19456    // bf16 [128][64] w transposed [d][c] (16384 B)
#define OFF_GSUM  35840    // float[128]
#define OFF_GSQ   36352    // float[128]
#define OFF_SCALE 36864    // float[128]
#define OFF_SHIFT 37376    // float[128]

typedef short short8 __attribute__((ext_vector_type(8)));
typedef float float4v __attribute__((ext_vector_type(4)));

static __device__ __forceinline__ float bf2f(ushort u) {
    union { uint i; float f; } c; c.i = ((uint)u) << 16; return c.f;
}
static __device__ __forceinline__ ushort f2bf(float f) {
    union { float f; uint i; } c; c.f = f;
    uint u = c.i;
    uint r = u + 0x7FFFu + ((u >> 16) & 1u);   // RNE
    return (ushort)(r >> 16);
}
static __device__ __forceinline__ uint packbf(float a, float b) {
    return (uint)f2bf(a) | ((uint)f2bf(b) << 16);
}
template<bool BF>
static __device__ __forceinline__ float ldg(const void* p, int i) {
    if (BF) return bf2f(((const ushort*)p)[i]);
    else    return ((const float*)p)[i];
}

// ---------------- K0: detect tensor dtype from adj bit patterns ----------------
// f32 0/1 adjacency: every 32b word is 0x00000000 or 0x3F800000.
// bf16 adjacency: words 0x00003F80 / 0x3F803F80 occur w.h.p. and are impossible for f32.
__global__ void k0_detect(const uint* __restrict__ adj_raw, char* __restrict__ ws) {
    __shared__ int s_found;
    if (threadIdx.x == 0) s_found = 0;
    __syncthreads();
    int found = 0;
    for (int i = threadIdx.x; i < 3698; i += blockDim.x) {
        uint wd = adj_raw[i];
        if (wd == 0x00003F80u || wd == 0x3F803F80u) found = 1;
    }
    if (found) atomicOr(&s_found, 1);
    __syncthreads();
    if (threadIdx.x == 0) *(int*)(ws + OFF_FLAG) = s_found;
}

// ---------------- K1: dense padded norm_adj (bf16) + wT + zero stats ----------------
template<bool BF>
__global__ void k1_prep(const void* __restrict__ adj, const void* __restrict__ w,
                        char* __restrict__ ws) {
    const int flag = *(const volatile int*)(ws + OFF_FLAG);
    if ((flag != 0) != BF) return;
    __shared__ float dinv[V];
    const int t = threadIdx.x;
    ushort* nadj = (ushort*)(ws + OFF_NADJ);
    ushort* wT   = (ushort*)(ws + OFF_WT);
    float*  gsum = (float*)(ws + OFF_GSUM);
    float*  gsq  = (float*)(ws + OFF_GSQ);

    if (t < V) {
        float s = 0.f;
        for (int v2 = 0; v2 < V; ++v2)
            s += ldg<BF>(adj, t * V + v2) + (v2 == t ? 1.f : 0.f);
        dinv[t] = rsqrtf(s);
    }
    __syncthreads();
    // dense padded nadj[u][v] = dinv[u]*(a+I)*dinv[v], zero for u,v >= 86
    for (int i = t; i < VP * VP; i += blockDim.x) {
        int u = i / VP, v2 = i % VP;
        float val = 0.f;
        if (u < V && v2 < V) {
            float a = ldg<BF>(adj, u * V + v2) + (v2 == u ? 1.f : 0.f);
            val = dinv[u] * a * dinv[v2];
        }
        nadj[i] = f2bf(val);
    }
    // w [c][d] -> wT [d][c] bf16
    for (int i = t; i < CIN * COUT; i += blockDim.x) {
        int cc = i >> 7, d = i & 127;
        wT[d * CIN + cc] = BF ? ((const ushort*)w)[i] : f2bf(((const float*)w)[i]);
    }
    if (t < COUT) { gsum[t] = 0.f; gsq[t] = 0.f; }
}

// ---------------- K2 pass: z = nadj @ (x @ w), all-MFMA, 8 bt per block ----------------
// Processes bt in PAIRS: one staging phase + one barrier covers two compute bodies.
// The yT-transpose barrier is removed: wave wv writes AND reads only s_yT rows
// d_own in [wv*16, wv*16+16) -> wave-local dependency, compiler lgkmcnt suffices.
// STATS=false: apply BN scale/shift + ReLU, store out. STATS=true: accumulate sum/sumsq.
#define NJ_STR 104   // shorts; 208 B rows: 16B-aligned, 2-way bank alias only
#define XS_STR 72    // 144 B rows
#define YT_STR 104

template<bool BF, bool STATS>
__global__ __launch_bounds__(512, 4) void k2_pass(const void* __restrict__ x,
                                                  char* __restrict__ ws,
                                                  void* __restrict__ outv) {
    const int flag = *(const volatile int*)(ws + OFF_FLAG);
    if ((flag != 0) != BF) return;

    __shared__ __align__(16) short s_nadj[VP * NJ_STR];     // 19968 B
    __shared__ __align__(16) short s_x[2 * VP * XS_STR];    // 27648 B (two bt halves)
    __shared__ __align__(16) short s_yT[COUT * YT_STR];     // 26624 B  (total 74240 B)

    const int tid  = threadIdx.x;
    const int lane = tid & 63, wv = tid >> 6;     // 8 waves
    const int col  = lane & 15, quad = lane >> 4;
    const int d_own = wv * 16 + col;              // this lane's output channel

    // nadj -> LDS once per block (global [96][96] -> [96][104])
    {
        const ushort* g = (const ushort*)(ws + OFF_NADJ);
        for (int i = tid; i < VP * 12; i += 512) {   // 12 x uint4 (8 shorts) per row
            int r = i / 12, j = i % 12;
            *(uint4*)&s_nadj[r * NJ_STR + j * 8] = *(const uint4*)&g[r * VP + j * 8];
        }
    }
    // w B-fragments live in registers for the whole kernel
    short8 bw[2];
    {
        const ushort* wt = (const ushort*)(ws + OFF_WT);
        bw[0] = *(const short8*)&wt[d_own * CIN + quad * 8];
        bw[1] = *(const short8*)&wt[d_own * CIN + 32 + quad * 8];
    }
    // zero-pad x rows 86..95 in BOTH halves (written once; staging only touches r < 86)
    if (tid < 160) {
        int r = V + (tid >> 4), j = tid & 15;
        *(uint2*)&s_x[r * XS_STR + j * 4] = (uint2){0u, 0u};
        *(uint2*)&s_x[VP * XS_STR + r * XS_STR + j * 4] = (uint2){0u, 0u};
    }
    float sc = 0.f, sh = 0.f;
    if (!STATS) {
        sc = ((const float*)(ws + OFF_SCALE))[d_own];
        sh = ((const float*)(ws + OFF_SHIFT))[d_own];
    }
    float s1 = 0.f, s2 = 0.f;

    for (int ip = 0; ip < 4; ++ip) {               // 4 pairs = 8 bt per block
        const int btp = blockIdx.x * 8 + ip * 2;
        __syncthreads();   // all prior reads of s_x / s_yT complete (also orders prologue)

        // ---- stage BOTH x slices -> LDS bf16 [86][64] x2 ----
        #pragma unroll
        for (int h = 0; h < 2; ++h) {
            short* sx = s_x + h * (VP * XS_STR);
            if (BF) {
                const ushort* xg = (const ushort*)x + (size_t)(btp + h) * (V * CIN);
                for (int i = tid; i < V * 8; i += 512) {     // 688 x uint4
                    int r = i >> 3, j = i & 7;
                    *(uint4*)&sx[r * XS_STR + j * 8] = *(const uint4*)&xg[r * CIN + j * 8];
                }
            } else {
                const float* xg = (const float*)x + (size_t)(btp + h) * (V * CIN);
                for (int i = tid; i < V * 16; i += 512) {    // 1376 x float4 -> uint2
                    int r = i >> 4, j = i & 15;
                    float4 f = *(const float4*)&xg[r * CIN + j * 4];
                    uint2 o; o.x = packbf(f.x, f.y); o.y = packbf(f.z, f.w);
                    *(uint2*)&sx[r * XS_STR + j * 4] = o;
                }
            }
        }
        __syncthreads();                   // both halves ready

        #pragma unroll
        for (int h = 0; h < 2; ++h) {
            const short* sx = s_x + h * (VP * XS_STR);
            const int bt = btp + h;

            // ---- stage A: y = x @ w  (M=96 rows v, N=16 own d-tile, K=64) ----
            float4v accy[6];
            #pragma unroll
            for (int m = 0; m < 6; ++m) accy[m] = (float4v){0.f, 0.f, 0.f, 0.f};
            #pragma unroll
            for (int ks = 0; ks < 2; ++ks) {
                #pragma unroll
                for (int m = 0; m < 6; ++m) {
                    short8 ax = *(const short8*)&sx[(m * 16 + col) * XS_STR + ks * 32 + quad * 8];
                    accy[m] = __builtin_amdgcn_mfma_f32_16x16x32_bf16(ax, bw[ks], accy[m], 0, 0, 0);
                }
            }
            // y D-frags -> yT[d][v] (wave-local rows; no barrier needed)
            #pragma unroll
            for (int m = 0; m < 6; ++m)
                #pragma unroll
                for (int r = 0; r < 4; ++r)
                    s_yT[d_own * YT_STR + m * 16 + quad * 4 + r] = (short)f2bf(accy[m][r]);

            // ---- stage B: z = nadj @ y  (M=96 rows u, N=16 own d-tile, K=96) ----
            float4v accz[6];
            #pragma unroll
            for (int m = 0; m < 6; ++m) accz[m] = (float4v){0.f, 0.f, 0.f, 0.f};
            #pragma unroll
            for (int ks = 0; ks < 3; ++ks) {
                short8 by = *(const short8*)&s_yT[d_own * YT_STR + ks * 32 + quad * 8];
                #pragma unroll
                for (int m = 0; m < 6; ++m) {
                    short8 an = *(const short8*)&s_nadj[(m * 16 + col) * NJ_STR + ks * 32 + quad * 8];
                    accz[m] = __builtin_amdgcn_mfma_f32_16x16x32_bf16(an, by, accz[m], 0, 0, 0);
                }
            }

            // ---- epilogue (D-frag: row u = m*16+quad*4+r, col d_own) ----
            if (STATS) {
                // pad rows u>=86 are exact zeros (nadj pad rows are zero) -> no guard
                #pragma unroll
                for (int m = 0; m < 6; ++m)
                    #pragma unroll
                    for (int r = 0; r < 4; ++r) {
                        float v2 = accz[m][r];
                        s1 += v2; s2 += v2 * v2;
                    }
            } else {
                const size_t base = (size_t)bt * (V * COUT) + d_own;
                #pragma unroll
                for (int m = 0; m < 6; ++m)
                    #pragma unroll
                    for (int r = 0; r < 4; ++r) {
                        int u = m * 16 + quad * 4 + r;
                        if (u < V) {
                            float val = fmaxf(accz[m][r] * sc + sh, 0.f);
                            if (BF) ((ushort*)outv)[base + (size_t)u * COUT] = f2bf(val);
                            else    ((float*)outv)[base + (size_t)u * COUT]  = val;
                        }
                    }
            }
        }
    }

    if (STATS) {
        // reduce over the 4 quads sharing d_own, then one atomic per channel per block
        s1 += __shfl_xor(s1, 16); s1 += __shfl_xor(s1, 32);
        s2 += __shfl_xor(s2, 16); s2 += __shfl_xor(s2, 32);
        if (quad == 0) {
            atomicAdd((float*)(ws + OFF_GSUM) + d_own, s1);
            atomicAdd((float*)(ws + OFF_GSQ)  + d_own, s2);
        }
    }
}

// ---------------- K3: finalize BN scale/shift ----------------
template<bool BF>
__global__ void k3_finalize(const void* __restrict__ gamma, const void* __restrict__ beta,
                            char* __restrict__ ws) {
    const int flag = *(const volatile int*)(ws + OFF_FLAG);
    if ((flag != 0) != BF) return;
    int d = threadIdx.x;
    if (d < COUT) {
        const float* gsum = (const float*)(ws + OFF_GSUM);
        const float* gsq  = (const float*)(ws + OFF_GSQ);
        float* scale = (float*)(ws + OFF_SCALE);
        float* shift = (float*)(ws + OFF_SHIFT);
        const float inv_n = 1.f / (float)NSTAT;
        float mean = gsum[d] * inv_n;
        float var  = gsq[d] * inv_n - mean * mean;
        float s    = ldg<BF>(gamma, d) * rsqrtf(var + 1e-5f);
        scale[d] = s;
        shift[d] = ldg<BF>(beta, d) - mean * s;
    }
}

extern "C" void kernel_launch(void* const* d_in, const int* in_sizes, int n_in,
                              void* d_out, int out_size, void* d_ws, size_t ws_size,
                              hipStream_t stream) {
    const void* x     = d_in[0];
    const void* adj   = d_in[1];
    const void* w     = d_in[2];
    const void* gamma = d_in[3];
    const void* beta  = d_in[4];
    char* ws = (char*)d_ws;

    // Host-side dtype sniff: if in_sizes is in BYTES, skip the mismatched template
    // chain entirely. If in_sizes is element counts (dtype-invariant), matches
    // neither pattern -> launch both chains (identical to proven baseline).
    const long long xb = (long long)in_sizes[0];
    const long long ab = (long long)in_sizes[1];
    const bool only_bf  = (ab == 86LL * 86 * 2) || (xb == 8192LL * 86 * 64 * 2);
    const bool only_f32 = !only_bf && ((ab == 86LL * 86 * 4) || (xb == 8192LL * 86 * 64 * 4));

    hipLaunchKernelGGL(k0_detect, dim3(1), dim3(256), 0, stream, (const uint*)adj, ws);
    if (!only_f32) hipLaunchKernelGGL((k1_prep<true>),  dim3(1), dim3(256), 0, stream, adj, w, ws);
    if (!only_bf)  hipLaunchKernelGGL((k1_prep<false>), dim3(1), dim3(256), 0, stream, adj, w, ws);
    // stats pass (no z write)
    if (!only_f32) hipLaunchKernelGGL((k2_pass<true,  true>),  dim3(1024), dim3(512), 0, stream, x, ws, d_out);
    if (!only_bf)  hipLaunchKernelGGL((k2_pass<false, true>),  dim3(1024), dim3(512), 0, stream, x, ws, d_out);
    if (!only_f32) hipLaunchKernelGGL((k3_finalize<true>),  dim3(1), dim3(128), 0, stream, gamma, beta, ws);
    if (!only_bf)  hipLaunchKernelGGL((k3_finalize<false>), dim3(1), dim3(128), 0, stream, gamma, beta, ws);
    // output pass (recompute z, fused BN+ReLU)
    if (!only_f32) hipLaunchKernelGGL((k2_pass<true,  false>), dim3(1024), dim3(512), 0, stream, x, ws, d_out);
    if (!only_bf)  hipLaunchKernelGGL((k2_pass<false, false>), dim3(1024), dim3(512), 0, stream, x, ws, d_out);
}